// Round 1
// 193.074 us; speedup vs baseline: 1.0576x; 1.0576x over previous
//
#include <hip/hip_runtime.h>

#define BATCH 4
#define SEQQ  2048
#define SEQKV 2048
#define NH    4      // kv heads (effective q heads after group-sum over g)
#define HD    64
#define IND   1024
// 0.125 (1/sqrt(64)) * log2(e): folded into Qr so softmax runs in exp2 domain
#define QSCL 0.18033688011112042f

typedef __attribute__((ext_vector_type(8))) short short8;   // 8 x bf16 raw bits
typedef __attribute__((ext_vector_type(4))) short s4v;      // 4 x bf16 raw bits
typedef __attribute__((ext_vector_type(4))) float floatx4;  // MFMA accum

// Fast exp2: raw v_exp_f32 on device; precise fallback elsewhere.
#if defined(__HIP_DEVICE_COMPILE__) && __has_builtin(__builtin_amdgcn_exp2f)
  #define EXP2(x) __builtin_amdgcn_exp2f(x)
#else
  #define EXP2(x) exp2f(x)
#endif

// 16x16x16 bf16 MFMA — gate on device pass (host pass lacks amdgcn __has_builtin).
#if defined(__HIP_DEVICE_COMPILE__)
  #if __has_builtin(__builtin_amdgcn_mfma_f32_16x16x16bf16_1k)
    #define MFMA16(a, b, c) __builtin_amdgcn_mfma_f32_16x16x16bf16_1k(a, b, c, 0, 0, 0)
  #elif __has_builtin(__builtin_amdgcn_mfma_f32_16x16x16_bf16)
    #define MFMA16(a, b, c) __builtin_amdgcn_mfma_f32_16x16x16_bf16(a, b, c, 0, 0, 0)
  #else
    #error "no 16x16x16 bf16 MFMA builtin on gfx950 device pass"
  #endif
#else
  #define MFMA16(a, b, c) (c)   // host pass placeholder, never executed
#endif
#define MFMA32(a, b, c) __builtin_amdgcn_mfma_f32_16x16x32_bf16(a, b, c, 0, 0, 0)

__device__ __forceinline__ short f2b(float f) {             // RNE
    unsigned u; __builtin_memcpy(&u, &f, 4);
    u = (u + 0x7fffu + ((u >> 16) & 1u)) >> 16;
    return (short)u;
}
__device__ __forceinline__ short8 cvt8(const float* p) {
    float4 a = *(const float4*)p;
    float4 b = *(const float4*)(p + 4);
    short8 r;
    r[0] = f2b(a.x); r[1] = f2b(a.y); r[2] = f2b(a.z); r[3] = f2b(a.w);
    r[4] = f2b(b.x); r[5] = f2b(b.y); r[6] = f2b(b.z); r[7] = f2b(b.w);
    return r;
}

// ---------------------------------------------------------------------------
// prep_all: LDS-tiled coalesced weight transposes + q/kv fp32->bf16.
// Grid 8448 x 256.
__global__ __launch_bounds__(256) void prep_all(
    const float* __restrict__ Wq, const float* __restrict__ Wk,
    const float* __restrict__ Wv, const float* __restrict__ Wo,
    const float* __restrict__ q, const float* __restrict__ kv,
    short* __restrict__ Wq_t, short* __restrict__ Wkv_t, short* __restrict__ Wo_t,
    short* __restrict__ qb, short* __restrict__ kvb) {
    __shared__ short Ts[64][65];
    int blk = blockIdx.x;
    if (blk < 256) {
        int c4 = threadIdx.x & 63, r4 = threadIdx.x >> 6;
        if (blk < 64) {                       // Wq (group-sum over g)
            int h = blk & 3, ib = blk >> 2;
#pragma unroll 4
            for (int jj = 0; jj < 16; ++jj) {
                int il = r4 * 16 + jj;
                float s = 0.f;
#pragma unroll
                for (int g = 0; g < 4; ++g)
                    s += Wq[(ib * 64 + il) * 1024 + (h * 4 + g) * 64 + c4];
                Ts[il][c4] = f2b(s);
            }
            __syncthreads();
#pragma unroll 4
            for (int jj = 0; jj < 16; ++jj) {
                int dl = r4 * 16 + jj;
                Wq_t[(h * 64 + dl) * 1024 + ib * 64 + c4] = Ts[c4][dl];
            }
        } else if (blk < 192) {               // Wk / Wv
            int t = blk - 64, ss = t >> 6; t &= 63;
            int ib = t >> 2, nb = t & 3;
            const float* W = ss ? Wv : Wk;
#pragma unroll 4
            for (int jj = 0; jj < 16; ++jj) {
                int il = r4 * 16 + jj;
                Ts[il][c4] = f2b(W[(ib * 64 + il) * 256 + nb * 64 + c4]);
            }
            __syncthreads();
#pragma unroll 4
            for (int jj = 0; jj < 16; ++jj) {
                int dl = r4 * 16 + jj;
                Wkv_t[(ss * 256 + nb * 64 + dl) * 1024 + ib * 64 + c4] = Ts[c4][dl];
            }
        } else {                              // Wo
            int t = blk - 192, kb = t >> 4, nb = t & 15;
#pragma unroll 4
            for (int jj = 0; jj < 16; ++jj) {
                int il = r4 * 16 + jj;
                Ts[il][c4] = f2b(Wo[(kb * 64 + il) * 1024 + nb * 64 + c4]);
            }
            __syncthreads();
#pragma unroll 4
            for (int jj = 0; jj < 16; ++jj) {
                int dl = r4 * 16 + jj;
                Wo_t[(nb * 64 + dl) * 256 + kb * 64 + c4] = Ts[c4][dl];
            }
        }
    } else if (blk < 4352) {
        long e = ((long)(blk - 256) * 256 + threadIdx.x) * 8;
        *(short8*)(qb + e) = cvt8(q + e);
    } else {
        long e = ((long)(blk - 4352) * 256 + threadIdx.x) * 8;
        *(short8*)(kvb + e) = cvt8(kv + e);
    }
}

// ---------------------------------------------------------------------------
// m97-style GEMM body: C[M][N] f32 = A[M][K] bf16 row-major x Wt[N][K] bf16 (B^T).
// 128x128 tile, BK=32, block 256 = 4 waves in 2x2 quadrants of 64x64.
// MODE 0: plain fp32 C store (final gemm).
// MODE 1: Q projection -> fused RoPE (QSCL folded) -> bf16 Qr[bh][s][64].
// MODE 2: KV projection -> cols<256: RoPE -> Kr; cols>=256: transpose -> Vt.
// RoPE in-epilogue: d-pair partner (dd^1) lives in adjacent lane -> shfl_xor(v,1);
// freq depends only on (ln>>1, nt parity); math bit-identical to old rope_all.
template <int MODE>
__device__ __forceinline__ void gemm128(
    const short* __restrict__ A, const short* __restrict__ Wt,
    int m0, int n0, int N, int K, short* As, short* Bs,
    float* __restrict__ C, const int* __restrict__ coords,
    short* __restrict__ ropeDst, short* __restrict__ vDst) {
    const int t = threadIdx.x;
    const int w = t >> 6, lane = t & 63, ln = lane & 15, quad = lane >> 4;
    const int wm = w >> 1, wn = w & 1;
    const int srow = lane >> 2, skc = (lane & 3) * 8;
    floatx4 acc[4][4];
#pragma unroll
    for (int mt = 0; mt < 4; ++mt)
#pragma unroll
        for (int nt = 0; nt < 4; ++nt) acc[mt][nt] = floatx4{0.f, 0.f, 0.f, 0.f};

    for (int ks = 0; ks < K; ks += 32) {
        __syncthreads();
#pragma unroll
        for (int i = 0; i < 2; ++i) {
            __builtin_amdgcn_global_load_lds(
                (const void*)(A + (long)(m0 + w * 32 + i * 16 + srow) * K + ks + skc),
                (void*)(As + (w * 2 + i) * 512), 16, 0, 0);
            __builtin_amdgcn_global_load_lds(
                (const void*)(Wt + (long)(n0 + w * 32 + i * 16 + srow) * K + ks + skc),
                (void*)(Bs + (w * 2 + i) * 512), 16, 0, 0);
        }
        __syncthreads();
        short8 af[4], bf[4];
#pragma unroll
        for (int mt = 0; mt < 4; ++mt)
            af[mt] = *(const short8*)(As + (wm * 64 + mt * 16 + ln) * 32 + quad * 8);
#pragma unroll
        for (int nt = 0; nt < 4; ++nt)
            bf[nt] = *(const short8*)(Bs + (wn * 64 + nt * 16 + ln) * 32 + quad * 8);
#pragma unroll
        for (int mt = 0; mt < 4; ++mt)
#pragma unroll
            for (int nt = 0; nt < 4; ++nt)
                acc[mt][nt] = MFMA32(af[mt], bf[nt], acc[mt][nt]);
    }

    if (MODE == 0) {
#pragma unroll
        for (int mt = 0; mt < 4; ++mt) {
            int row0 = m0 + wm * 64 + mt * 16 + quad * 4;
#pragma unroll
            for (int nt = 0; nt < 4; ++nt) {
                int col = n0 + wn * 64 + nt * 16 + ln;
#pragma unroll
                for (int r = 0; r < 4; ++r)
                    C[(long)(row0 + r) * N + col] = acc[mt][nt][r];
            }
        }
    } else {
        const int wn_col = n0 + wn * 64;          // wave covers one 64-col head slab
        if (MODE == 1 || wn_col < 256) {          // ---- rope path (Q or K)
            const int h = (wn_col >> 6) & 3;
            const float scl = (MODE == 1) ? QSCL : 1.0f;
            const float L = -0.5756462732485114f; // -ln(1e4)/16
            const float fA = __expf((float)(ln >> 1) * L);
            const float fB = __expf((float)(8 + (ln >> 1)) * L);
            const float sgn = (ln & 1) ? 1.0f : -1.0f;
#pragma unroll
            for (int mt = 0; mt < 4; ++mt) {
                int row0 = m0 + wm * 64 + mt * 16 + quad * 4;
#pragma unroll
                for (int r = 0; r < 4; ++r) {
                    int row = row0 + r;
                    float c0 = (float)coords[row * 2];
                    float c1 = (float)coords[row * 2 + 1];
                    float snv[4], csv[4];
                    __sincosf(c0 * fA, &snv[0], &csv[0]);   // nt=0: axis0, j=ln>>1
                    __sincosf(c0 * fB, &snv[1], &csv[1]);   // nt=1: axis0, j=8+ln>>1
                    __sincosf(c1 * fA, &snv[2], &csv[2]);   // nt=2: axis1
                    __sincosf(c1 * fB, &snv[3], &csv[3]);   // nt=3: axis1
                    long rbase = ((long)((row >> 11) * 4 + h) * 2048 + (row & 2047)) * 64;
#pragma unroll
                    for (int nt = 0; nt < 4; ++nt) {
                        float v = acc[mt][nt][r];
                        float p = __shfl_xor(v, 1, 64);     // pair partner (dd^1)
                        float o = v * (csv[nt] * scl) + p * (snv[nt] * (scl * sgn));
                        ropeDst[rbase + nt * 16 + ln] = f2b(o);
                    }
                }
            }
        } else {                                  // ---- V transpose path
            const int h = ((wn_col - 256) >> 6) & 3;
#pragma unroll
            for (int mt = 0; mt < 4; ++mt) {
                int row0 = m0 + wm * 64 + mt * 16 + quad * 4;
                int b = row0 >> 11, s0 = row0 & 2047;
#pragma unroll
                for (int nt = 0; nt < 4; ++nt) {
                    s4v ov;                       // 4 consecutive s per lane
#pragma unroll
                    for (int r = 0; r < 4; ++r) ov[r] = f2b(acc[mt][nt][r]);
                    *(s4v*)(vDst + (long)((b * 4 + h) * 64 + nt * 16 + ln) * 2048 + s0) = ov;
                }
            }
        }
    }
}

__global__ __launch_bounds__(256) void proj_gemm(
    const short* __restrict__ qb, const short* __restrict__ kvb,
    const short* __restrict__ Wq_t, const short* __restrict__ Wkv_t,
    const int* __restrict__ qc, const int* __restrict__ kvc,
    short* __restrict__ Qr, short* __restrict__ Kr, short* __restrict__ Vt) {
    __shared__ __align__(16) short As[128 * 32];
    __shared__ __align__(16) short Bs[128 * 32];
    int id = blockIdx.x;
    if (id < 128)
        gemm128<1>(qb, Wq_t, (id >> 1) * 128, (id & 1) * 128, 256, 1024, As, Bs,
                   nullptr, qc, Qr, nullptr);
    else {
        int t = id - 128;
        gemm128<2>(kvb, Wkv_t, (t >> 2) * 128, (t & 3) * 128, 512, 1024, As, Bs,
                   nullptr, kvc, Kr, Vt);
    }
}

__global__ __launch_bounds__(256) void final_gemm(
    const short* __restrict__ Ob, const short* __restrict__ Wo_t, float* __restrict__ out) {
    __shared__ __align__(16) short As[128 * 32];
    __shared__ __align__(16) short Bs[128 * 32];
    gemm128<0>(Ob, Wo_t, blockIdx.x * 128, blockIdx.y * 128, 1024, 256, As, Bs,
               out, nullptr, nullptr, nullptr);
}

// ---------------------------------------------------------------------------
// Flash attention, LDS-staged (m97-style), TA-friendly. Grid 1024 x 256.
// Block = 128 q (4 waves x 32 q), kv-split-4 (512 kv/block), kv-tile 64.
// K-tile [64 kv][64 d] and V^T-tile [64 d][64 kv] staged via global_load_lds
// width-16 with XOR chunk swizzle (16B chunk index ^ (row&7)) -> conflict-free
// ds_read fragments, zero per-lane global gathers in the loop.
// S^T = K Q^T (MFMA32); C-layout (kv=quad*4+r, q=ln) == MFMA16 B-frag layout
// of O^T = V^T P^T -> exp2 in-register. No shift; l via ones-MFMA.
__global__ __launch_bounds__(256, 4) void attn_kernel(
    const short* __restrict__ Qr, const short* __restrict__ Kr,
    const short* __restrict__ Vt, float* __restrict__ Op, float* __restrict__ Lp) {
    __shared__ __align__(16) short Kls[64 * 64];   // [kv][d] chunks swizzled
    __shared__ __align__(16) short Vls[64 * 64];   // [d][kv] chunks swizzled
    const int blk = blockIdx.x;
    const int bh = blk & 15, sp = (blk >> 4) & 3, qg = blk >> 6;
    const int w = threadIdx.x >> 6, lane = threadIdx.x & 63;
    const int ln = lane & 15, quad = lane >> 4;
    const int q0 = qg * 128 + w * 32;
    const short* Qb = Qr + (long)bh * SEQKV * HD;
    const short* Kb = Kr + (long)bh * SEQKV * HD;
    const short* Vb = Vt + (long)bh * HD * SEQKV;

    // staging addressing: each wave-inst covers 8 rows (8 lanes/row, 16B/lane),
    // global chunk swizzled by row&7 so LDS slot (lane&7) holds chunk (lane&7)^(row&7)
    const int srow = lane >> 3;                       // 0..7 within 8-row group
    const int schk = (lane & 7) ^ (srow & 7);         // swizzled 16B chunk
    const long kstage0 = (long)(w * 16 + srow) * HD + schk * 8;        // + kt*HD
    const long vstage0 = (long)(w * 16 + srow) * SEQKV + schk * 8;     // + kt

    short8 qf[2][2];                           // B-frag of Q^T: [qsub][d-chunk32]
#pragma unroll
    for (int qs = 0; qs < 2; ++qs)
#pragma unroll
        for (int ck = 0; ck < 2; ++ck)
            qf[qs][ck] = *(const short8*)(Qb + (long)(q0 + qs * 16 + ln) * HD + ck * 32 + quad * 8);

    s4v ones;
#pragma unroll
    for (int j = 0; j < 4; ++j) ones[j] = (short)0x3F80;   // bf16 1.0

    floatx4 o[2][4], ol[2];
#pragma unroll
    for (int qs = 0; qs < 2; ++qs) {
        ol[qs] = floatx4{0.f, 0.f, 0.f, 0.f};
#pragma unroll
        for (int nt = 0; nt < 4; ++nt) o[qs][nt] = floatx4{0.f, 0.f, 0.f, 0.f};
    }

    // precomputed swizzled ds_read offsets
    const int ln7 = ln & 7;
    int koff[2];                               // S A-frag: row t*16+ln, chunk (ck*4+quad)^ln7
#pragma unroll
    for (int ck = 0; ck < 2; ++ck) koff[ck] = ln * 64 + ((ck * 4 + quad) ^ ln7) * 8;
    int voff[4];                               // V A-frag: row nt*16+ln, chunk (t*2+(quad>>1))^ln7
#pragma unroll
    for (int t = 0; t < 4; ++t) voff[t] = ln * 64 + ((t * 2 + (quad >> 1)) ^ ln7) * 8 + (quad & 1) * 4;

    for (int kt = sp * 512; kt < sp * 512 + 512; kt += 64) {
        __syncthreads();                       // prev tile reads done
#pragma unroll
        for (int i = 0; i < 2; ++i) {
            __builtin_amdgcn_global_load_lds(
                (const void*)(Kb + (long)kt * HD + kstage0 + (long)i * 8 * HD),
                (void*)(Kls + (w * 16 + i * 8) * 64), 16, 0, 0);
            __builtin_amdgcn_global_load_lds(
                (const void*)(Vb + kt + vstage0 + (long)i * 8 * SEQKV),
                (void*)(Vls + (w * 16 + i * 8) * 64), 16, 0, 0);
        }
        __syncthreads();                       // staged (vmcnt drained at barrier)

#pragma unroll
        for (int t = 0; t < 4; ++t) {
            short8 a0 = *(const short8*)(Kls + t * 1024 + koff[0]);
            short8 a1 = *(const short8*)(Kls + t * 1024 + koff[1]);
            floatx4 st0 = {0.f, 0.f, 0.f, 0.f}, st1 = {0.f, 0.f, 0.f, 0.f};
            st0 = MFMA32(a0, qf[0][0], st0);
            st1 = MFMA32(a0, qf[1][0], st1);
            st0 = MFMA32(a1, qf[0][1], st0);
            st1 = MFMA32(a1, qf[1][1], st1);
            s4v pt0, pt1;                      // P^T B-frag, in-register
#pragma unroll
            for (int j = 0; j < 4; ++j) {
                float p0 = EXP2(st0[j]);
                float p1 = EXP2(st1[j]);
                unsigned u0, u1;
                __builtin_memcpy(&u0, &p0, 4); __builtin_memcpy(&u1, &p1, 4);
                pt0[j] = (short)((u0 + 0x8000u) >> 16);
                pt1[j] = (short)((u1 + 0x8000u) >> 16);
            }
#pragma unroll
            for (int nt = 0; nt < 4; ++nt) {   // O^T += V^T P^T
                s4v vf = *(const s4v*)(Vls + nt * 1024 + voff[t]);
                o[0][nt] = MFMA16(vf, pt0, o[0][nt]);
                o[1][nt] = MFMA16(vf, pt1, o[1][nt]);
            }
            ol[0] = MFMA16(ones, pt0, ol[0]);  // l += 1^T P^T
            ol[1] = MFMA16(ones, pt1, ol[1]);
        }
    }
    // epilogue: store partial O (d = nt*16+quad*4+r, q = ln) + l
#pragma unroll
    for (int qs = 0; qs < 2; ++qs) {
        long qrow = (long)(sp * 16 + bh) * 2048 + q0 + qs * 16 + ln;
        if (quad == 0) Lp[qrow] = ol[qs][0];
#pragma unroll
        for (int nt = 0; nt < 4; ++nt)
            *(floatx4*)(Op + qrow * 64 + nt * 16 + quad * 4) = o[qs][nt];
    }
}

// ---------------------------------------------------------------------------
// Combine kv-split partials: O = sum_s Op / sum_s l -> Ob[b*s][256] bf16.
__global__ __launch_bounds__(256) void combine_kernel(
    const float* __restrict__ Op, const float* __restrict__ Lp, short* __restrict__ Ob) {
    int row = blockIdx.x * 4 + (threadIdx.x >> 6);   // bh*2048 + q
    int d = threadIdx.x & 63;
    int bh = row >> 11, qq = row & 2047;
    int b = bh >> 2, h = bh & 3;
    float os = 0.f, ls = 0.f;
#pragma unroll
    for (int s = 0; s < 4; ++s) {
        long rr = (long)(s * 16 + bh) * 2048 + qq;
        os += Op[rr * 64 + d];
        ls += Lp[rr];
    }
    Ob[((long)(b * 2048 + qq)) * 256 + h * 64 + d] = f2b(os / ls);
}

// ---------------------------------------------------------------------------
extern "C" void kernel_launch(void* const* d_in, const int* in_sizes, int n_in,
                              void* d_out, int out_size, void* d_ws, size_t ws_size,
                              hipStream_t stream) {
    const float* q   = (const float*)d_in[0];
    const int*   qc  = (const int*)d_in[1];
    const float* kv  = (const float*)d_in[2];
    const int*   kvc = (const int*)d_in[3];
    const float* Wq  = (const float*)d_in[4];
    const float* Wk  = (const float*)d_in[5];
    const float* Wv  = (const float*)d_in[6];
    const float* Wo  = (const float*)d_in[7];
    float* out = (float*)d_out;

    char* ws = (char*)d_ws;
    const size_t MB = 1024 * 1024;
    short* Wq_t  = (short*)(ws);                 // 0.5 MB  [256][1024]
    short* Wkv_t = (short*)(ws + MB / 2);        // 1.0 MB  [512][1024]
    short* Wo_t  = (short*)(ws + 3 * MB / 2);    // 0.5 MB  [1024][256]
    short* qb    = (short*)(ws + 2 * MB);        // 16 MB   [8192][1024] bf16
    short* kvb   = (short*)(ws + 18 * MB);       // 16 MB
    // rope outputs written directly by proj_gemm epilogue (no fp32 Qp/KVp):
    short* Qr    = (short*)(ws + 34 * MB);       // 4 MB  [16][2048][64]
    short* Kr    = (short*)(ws + 38 * MB);       // 4 MB
    short* Vt    = (short*)(ws + 42 * MB);       // 4 MB  [16][64][2048]
    short* Ob    = (short*)(ws + 46 * MB);       // 4 MB  [8192][256]
    float* Opart = (float*)(ws + 50 * MB);       // 32 MB [4 split][16 bh][2048 q][64 d]
    float* Lpart = (float*)(ws + 82 * MB);       // 0.5 MB [4][16][2048]

    hipLaunchKernelGGL(prep_all, dim3(8448), dim3(256), 0, stream,
                       Wq, Wk, Wv, Wo, q, kv, Wq_t, Wkv_t, Wo_t, qb, kvb);
    hipLaunchKernelGGL(proj_gemm, dim3(384), dim3(256), 0, stream,
                       qb, kvb, Wq_t, Wkv_t, qc, kvc, Qr, Kr, Vt);
    hipLaunchKernelGGL(attn_kernel, dim3(1024), dim3(256), 0, stream,
                       Qr, Kr, Vt, Opart, Lpart);
    hipLaunchKernelGGL(combine_kernel, dim3(8192), dim3(256), 0, stream,
                       Opart, Lpart, Ob);
    hipLaunchKernelGGL(final_gemm, dim3(64, 8), dim3(256), 0, stream, Ob, Wo_t, out);
}

// Round 2
// 191.251 us; speedup vs baseline: 1.0677x; 1.0095x over previous
//
#include <hip/hip_runtime.h>

#define BATCH 4
#define SEQQ  2048
#define SEQKV 2048
#define NH    4      // kv heads (effective q heads after group-sum over g)
#define HD    64
#define IND   1024
// 0.125 (1/sqrt(64)) * log2(e): folded into Qr so softmax runs in exp2 domain
#define QSCL 0.18033688011112042f

typedef __attribute__((ext_vector_type(8))) short short8;   // 8 x bf16 raw bits
typedef __attribute__((ext_vector_type(4))) short s4v;      // 4 x bf16 raw bits
typedef __attribute__((ext_vector_type(4))) float floatx4;  // MFMA accum

// Fast exp2: raw v_exp_f32 on device; precise fallback elsewhere.
#if defined(__HIP_DEVICE_COMPILE__) && __has_builtin(__builtin_amdgcn_exp2f)
  #define EXP2(x) __builtin_amdgcn_exp2f(x)
#else
  #define EXP2(x) exp2f(x)
#endif

// 16x16x16 bf16 MFMA — gate on device pass (host pass lacks amdgcn __has_builtin).
#if defined(__HIP_DEVICE_COMPILE__)
  #if __has_builtin(__builtin_amdgcn_mfma_f32_16x16x16bf16_1k)
    #define MFMA16(a, b, c) __builtin_amdgcn_mfma_f32_16x16x16bf16_1k(a, b, c, 0, 0, 0)
  #elif __has_builtin(__builtin_amdgcn_mfma_f32_16x16x16_bf16)
    #define MFMA16(a, b, c) __builtin_amdgcn_mfma_f32_16x16x16_bf16(a, b, c, 0, 0, 0)
  #else
    #error "no 16x16x16 bf16 MFMA builtin on gfx950 device pass"
  #endif
#else
  #define MFMA16(a, b, c) (c)   // host pass placeholder, never executed
#endif
#define MFMA32(a, b, c) __builtin_amdgcn_mfma_f32_16x16x32_bf16(a, b, c, 0, 0, 0)

__device__ __forceinline__ short f2b(float f) {             // RNE
    unsigned u; __builtin_memcpy(&u, &f, 4);
    u = (u + 0x7fffu + ((u >> 16) & 1u)) >> 16;
    return (short)u;
}
__device__ __forceinline__ short8 cvt8(const float* p) {
    float4 a = *(const float4*)p;
    float4 b = *(const float4*)(p + 4);
    short8 r;
    r[0] = f2b(a.x); r[1] = f2b(a.y); r[2] = f2b(a.z); r[3] = f2b(a.w);
    r[4] = f2b(b.x); r[5] = f2b(b.y); r[6] = f2b(b.z); r[7] = f2b(b.w);
    return r;
}

// ---------------------------------------------------------------------------
// prep_all: LDS-tiled coalesced weight transposes + q/kv fp32->bf16.
// Grid 4352 x 256 (256 weight blocks + 2048 q-cvt + 2048 kv-cvt, 16 elem/thr).
__global__ __launch_bounds__(256) void prep_all(
    const float* __restrict__ Wq, const float* __restrict__ Wk,
    const float* __restrict__ Wv, const float* __restrict__ Wo,
    const float* __restrict__ q, const float* __restrict__ kv,
    short* __restrict__ Wq_t, short* __restrict__ Wkv_t, short* __restrict__ Wo_t,
    short* __restrict__ qb, short* __restrict__ kvb) {
    __shared__ short Ts[64][65];
    int blk = blockIdx.x;
    if (blk < 256) {
        int c4 = threadIdx.x & 63, r4 = threadIdx.x >> 6;
        if (blk < 64) {                       // Wq (group-sum over g)
            int h = blk & 3, ib = blk >> 2;
#pragma unroll 4
            for (int jj = 0; jj < 16; ++jj) {
                int il = r4 * 16 + jj;
                float s = 0.f;
#pragma unroll
                for (int g = 0; g < 4; ++g)
                    s += Wq[(ib * 64 + il) * 1024 + (h * 4 + g) * 64 + c4];
                Ts[il][c4] = f2b(s);
            }
            __syncthreads();
#pragma unroll 4
            for (int jj = 0; jj < 16; ++jj) {
                int dl = r4 * 16 + jj;
                Wq_t[(h * 64 + dl) * 1024 + ib * 64 + c4] = Ts[c4][dl];
            }
        } else if (blk < 192) {               // Wk / Wv
            int t = blk - 64, ss = t >> 6; t &= 63;
            int ib = t >> 2, nb = t & 3;
            const float* W = ss ? Wv : Wk;
#pragma unroll 4
            for (int jj = 0; jj < 16; ++jj) {
                int il = r4 * 16 + jj;
                Ts[il][c4] = f2b(W[(ib * 64 + il) * 256 + nb * 64 + c4]);
            }
            __syncthreads();
#pragma unroll 4
            for (int jj = 0; jj < 16; ++jj) {
                int dl = r4 * 16 + jj;
                Wkv_t[(ss * 256 + nb * 64 + dl) * 1024 + ib * 64 + c4] = Ts[c4][dl];
            }
        } else {                              // Wo
            int t = blk - 192, kb = t >> 4, nb = t & 15;
#pragma unroll 4
            for (int jj = 0; jj < 16; ++jj) {
                int il = r4 * 16 + jj;
                Ts[il][c4] = f2b(Wo[(kb * 64 + il) * 1024 + nb * 64 + c4]);
            }
            __syncthreads();
#pragma unroll 4
            for (int jj = 0; jj < 16; ++jj) {
                int dl = r4 * 16 + jj;
                Wo_t[(nb * 64 + dl) * 256 + kb * 64 + c4] = Ts[c4][dl];
            }
        }
    } else if (blk < 2304) {
        long e = ((long)(blk - 256) * 256 + threadIdx.x) * 16;
        *(short8*)(qb + e)     = cvt8(q + e);
        *(short8*)(qb + e + 8) = cvt8(q + e + 8);
    } else {
        long e = ((long)(blk - 2304) * 256 + threadIdx.x) * 16;
        *(short8*)(kvb + e)     = cvt8(kv + e);
        *(short8*)(kvb + e + 8) = cvt8(kv + e + 8);
    }
}

// ---------------------------------------------------------------------------
// m97-style GEMM body: C[M][N] f32 = A[M][K] bf16 row-major x Wt[N][K] bf16 (B^T).
// 128x128 tile, BK=32, block 256 = 4 waves in 2x2 quadrants of 64x64.
// MODE 0: plain fp32 C store (final gemm).
// MODE 1: Q projection -> fused RoPE (QSCL folded) -> bf16 Qr[bh][s][64].
// MODE 2: KV projection -> cols<256: RoPE -> Kr; cols>=256: transpose -> Vt.
// RoPE in-epilogue: d-pair partner (dd^1) lives in adjacent lane -> shfl_xor(v,1);
// freq depends only on (ln>>1, nt parity); math bit-identical to old rope_all.
template <int MODE>
__device__ __forceinline__ void gemm128(
    const short* __restrict__ A, const short* __restrict__ Wt,
    int m0, int n0, int N, int K, short* As, short* Bs,
    float* __restrict__ C, const int* __restrict__ coords,
    short* __restrict__ ropeDst, short* __restrict__ vDst) {
    const int t = threadIdx.x;
    const int w = t >> 6, lane = t & 63, ln = lane & 15, quad = lane >> 4;
    const int wm = w >> 1, wn = w & 1;
    const int srow = lane >> 2, skc = (lane & 3) * 8;
    floatx4 acc[4][4];
#pragma unroll
    for (int mt = 0; mt < 4; ++mt)
#pragma unroll
        for (int nt = 0; nt < 4; ++nt) acc[mt][nt] = floatx4{0.f, 0.f, 0.f, 0.f};

    for (int ks = 0; ks < K; ks += 32) {
        __syncthreads();
#pragma unroll
        for (int i = 0; i < 2; ++i) {
            __builtin_amdgcn_global_load_lds(
                (const void*)(A + (long)(m0 + w * 32 + i * 16 + srow) * K + ks + skc),
                (void*)(As + (w * 2 + i) * 512), 16, 0, 0);
            __builtin_amdgcn_global_load_lds(
                (const void*)(Wt + (long)(n0 + w * 32 + i * 16 + srow) * K + ks + skc),
                (void*)(Bs + (w * 2 + i) * 512), 16, 0, 0);
        }
        __syncthreads();
        short8 af[4], bf[4];
#pragma unroll
        for (int mt = 0; mt < 4; ++mt)
            af[mt] = *(const short8*)(As + (wm * 64 + mt * 16 + ln) * 32 + quad * 8);
#pragma unroll
        for (int nt = 0; nt < 4; ++nt)
            bf[nt] = *(const short8*)(Bs + (wn * 64 + nt * 16 + ln) * 32 + quad * 8);
#pragma unroll
        for (int mt = 0; mt < 4; ++mt)
#pragma unroll
            for (int nt = 0; nt < 4; ++nt)
                acc[mt][nt] = MFMA32(af[mt], bf[nt], acc[mt][nt]);
    }

    if (MODE == 0) {
#pragma unroll
        for (int mt = 0; mt < 4; ++mt) {
            int row0 = m0 + wm * 64 + mt * 16 + quad * 4;
#pragma unroll
            for (int nt = 0; nt < 4; ++nt) {
                int col = n0 + wn * 64 + nt * 16 + ln;
#pragma unroll
                for (int r = 0; r < 4; ++r)
                    C[(long)(row0 + r) * N + col] = acc[mt][nt][r];
            }
        }
    } else {
        const int wn_col = n0 + wn * 64;          // wave covers one 64-col head slab
        if (MODE == 1 || wn_col < 256) {          // ---- rope path (Q or K)
            const int h = (wn_col >> 6) & 3;
            const float scl = (MODE == 1) ? QSCL : 1.0f;
            const float L = -0.5756462732485114f; // -ln(1e4)/16
            const float fA = __expf((float)(ln >> 1) * L);
            const float fB = __expf((float)(8 + (ln >> 1)) * L);
            const float sgn = (ln & 1) ? 1.0f : -1.0f;
#pragma unroll
            for (int mt = 0; mt < 4; ++mt) {
                int row0 = m0 + wm * 64 + mt * 16 + quad * 4;
#pragma unroll
                for (int r = 0; r < 4; ++r) {
                    int row = row0 + r;
                    float c0 = (float)coords[row * 2];
                    float c1 = (float)coords[row * 2 + 1];
                    float snv[4], csv[4];
                    __sincosf(c0 * fA, &snv[0], &csv[0]);   // nt=0: axis0, j=ln>>1
                    __sincosf(c0 * fB, &snv[1], &csv[1]);   // nt=1: axis0, j=8+ln>>1
                    __sincosf(c1 * fA, &snv[2], &csv[2]);   // nt=2: axis1
                    __sincosf(c1 * fB, &snv[3], &csv[3]);   // nt=3: axis1
                    long rbase = ((long)((row >> 11) * 4 + h) * 2048 + (row & 2047)) * 64;
#pragma unroll
                    for (int nt = 0; nt < 4; ++nt) {
                        float v = acc[mt][nt][r];
                        float p = __shfl_xor(v, 1, 64);     // pair partner (dd^1)
                        float o = v * (csv[nt] * scl) + p * (snv[nt] * (scl * sgn));
                        ropeDst[rbase + nt * 16 + ln] = f2b(o);
                    }
                }
            }
        } else {                                  // ---- V transpose path
            const int h = ((wn_col - 256) >> 6) & 3;
#pragma unroll
            for (int mt = 0; mt < 4; ++mt) {
                int row0 = m0 + wm * 64 + mt * 16 + quad * 4;
                int b = row0 >> 11, s0 = row0 & 2047;
#pragma unroll
                for (int nt = 0; nt < 4; ++nt) {
                    s4v ov;                       // 4 consecutive s per lane
#pragma unroll
                    for (int r = 0; r < 4; ++r) ov[r] = f2b(acc[mt][nt][r]);
                    *(s4v*)(vDst + (long)((b * 4 + h) * 64 + nt * 16 + ln) * 2048 + s0) = ov;
                }
            }
        }
    }
}

__global__ __launch_bounds__(256) void proj_gemm(
    const short* __restrict__ qb, const short* __restrict__ kvb,
    const short* __restrict__ Wq_t, const short* __restrict__ Wkv_t,
    const int* __restrict__ qc, const int* __restrict__ kvc,
    short* __restrict__ Qr, short* __restrict__ Kr, short* __restrict__ Vt) {
    __shared__ __align__(16) short As[128 * 32];
    __shared__ __align__(16) short Bs[128 * 32];
    int id = blockIdx.x;
    if (id < 128)
        gemm128<1>(qb, Wq_t, (id >> 1) * 128, (id & 1) * 128, 256, 1024, As, Bs,
                   nullptr, qc, Qr, nullptr);
    else {
        int t = id - 128;
        gemm128<2>(kvb, Wkv_t, (t >> 2) * 128, (t & 3) * 128, 512, 1024, As, Bs,
                   nullptr, kvc, Kr, Vt);
    }
}

__global__ __launch_bounds__(256) void final_gemm(
    const short* __restrict__ Ob, const short* __restrict__ Wo_t, float* __restrict__ out) {
    __shared__ __align__(16) short As[128 * 32];
    __shared__ __align__(16) short Bs[128 * 32];
    gemm128<0>(Ob, Wo_t, blockIdx.x * 128, blockIdx.y * 128, 1024, 256, As, Bs,
               out, nullptr, nullptr, nullptr);
}

// ---------------------------------------------------------------------------
// Flash attention, LDS-staged, 2-phase double-buffered (T3-minimum template):
// STAGE(tile t+1 -> buf^1) issued BEFORE compute(buf), ONE __syncthreads per
// tile (its compiler-emitted vmcnt(0)+lgkmcnt(0) drain is exactly the wait).
// Buffer hazard safe: buf^1 was last ds-read before the previous barrier.
// Grid 1024 x 256. Block = 128 q (4 waves x 32 q), kv-split-4, kv-tile 64.
// K-tile [64 kv][64 d] and V^T-tile [64 d][64 kv] staged via global_load_lds
// width-16 with XOR chunk swizzle (16B chunk index ^ (row&7)) -> conflict-free
// ds_read fragments. S^T = K Q^T (MFMA32); exp2 in-register; l via ones-MFMA.
__global__ __launch_bounds__(256, 4) void attn_kernel(
    const short* __restrict__ Qr, const short* __restrict__ Kr,
    const short* __restrict__ Vt, float* __restrict__ Op, float* __restrict__ Lp) {
    __shared__ __align__(16) short Kls[2][64 * 64];   // [kv][d] chunks swizzled
    __shared__ __align__(16) short Vls[2][64 * 64];   // [d][kv] chunks swizzled
    const int blk = blockIdx.x;
    const int bh = blk & 15, sp = (blk >> 4) & 3, qg = blk >> 6;
    const int w = threadIdx.x >> 6, lane = threadIdx.x & 63;
    const int ln = lane & 15, quad = lane >> 4;
    const int q0 = qg * 128 + w * 32;
    const short* Qb = Qr + (long)bh * SEQKV * HD;
    const short* Kb = Kr + (long)bh * SEQKV * HD;
    const short* Vb = Vt + (long)bh * HD * SEQKV;

    // staging addressing: each wave-inst covers 8 rows (8 lanes/row, 16B/lane),
    // global chunk swizzled by row&7 so LDS slot (lane&7) holds chunk (lane&7)^(row&7)
    const int srow = lane >> 3;                       // 0..7 within 8-row group
    const int schk = (lane & 7) ^ (srow & 7);         // swizzled 16B chunk
    const long kstage0 = (long)(w * 16 + srow) * HD + schk * 8;        // + kt*HD
    const long vstage0 = (long)(w * 16 + srow) * SEQKV + schk * 8;     // + kt

    short8 qf[2][2];                           // B-frag of Q^T: [qsub][d-chunk32]
#pragma unroll
    for (int qs = 0; qs < 2; ++qs)
#pragma unroll
        for (int ck = 0; ck < 2; ++ck)
            qf[qs][ck] = *(const short8*)(Qb + (long)(q0 + qs * 16 + ln) * HD + ck * 32 + quad * 8);

    s4v ones;
#pragma unroll
    for (int j = 0; j < 4; ++j) ones[j] = (short)0x3F80;   // bf16 1.0

    floatx4 o[2][4], ol[2];
#pragma unroll
    for (int qs = 0; qs < 2; ++qs) {
        ol[qs] = floatx4{0.f, 0.f, 0.f, 0.f};
#pragma unroll
        for (int nt = 0; nt < 4; ++nt) o[qs][nt] = floatx4{0.f, 0.f, 0.f, 0.f};
    }

    // precomputed swizzled ds_read offsets
    const int ln7 = ln & 7;
    int koff[2];                               // S A-frag: row t*16+ln, chunk (ck*4+quad)^ln7
#pragma unroll
    for (int ck = 0; ck < 2; ++ck) koff[ck] = ln * 64 + ((ck * 4 + quad) ^ ln7) * 8;
    int voff[4];                               // V A-frag: row nt*16+ln, chunk (t*2+(quad>>1))^ln7
#pragma unroll
    for (int t = 0; t < 4; ++t) voff[t] = ln * 64 + ((t * 2 + (quad >> 1)) ^ ln7) * 8 + (quad & 1) * 4;

    const int kt0 = sp * 512;
#define STAGE(kt, sel)                                                              \
    do {                                                                            \
        _Pragma("unroll")                                                           \
        for (int i = 0; i < 2; ++i) {                                               \
            __builtin_amdgcn_global_load_lds(                                       \
                (const void*)(Kb + (long)(kt) * HD + kstage0 + (long)i * 8 * HD),   \
                (void*)(Kls[sel] + (w * 16 + i * 8) * 64), 16, 0, 0);               \
            __builtin_amdgcn_global_load_lds(                                       \
                (const void*)(Vb + (kt) + vstage0 + (long)i * 8 * SEQKV),           \
                (void*)(Vls[sel] + (w * 16 + i * 8) * 64), 16, 0, 0);               \
        }                                                                           \
    } while (0)

    STAGE(kt0, 0);
    __syncthreads();                           // vmcnt(0) drain + barrier
    int cur = 0;
    for (int tt = 0; tt < 8; ++tt) {
        if (tt < 7) STAGE(kt0 + (tt + 1) * 64, cur ^ 1);   // prefetch next tile
        const short* Kc = Kls[cur];
        const short* Vc = Vls[cur];
#pragma unroll
        for (int t = 0; t < 4; ++t) {
            short8 a0 = *(const short8*)(Kc + t * 1024 + koff[0]);
            short8 a1 = *(const short8*)(Kc + t * 1024 + koff[1]);
            floatx4 st0 = {0.f, 0.f, 0.f, 0.f}, st1 = {0.f, 0.f, 0.f, 0.f};
            st0 = MFMA32(a0, qf[0][0], st0);
            st1 = MFMA32(a0, qf[1][0], st1);
            st0 = MFMA32(a1, qf[0][1], st0);
            st1 = MFMA32(a1, qf[1][1], st1);
            s4v pt0, pt1;                      // P^T B-frag, in-register
#pragma unroll
            for (int j = 0; j < 4; ++j) {
                float p0 = EXP2(st0[j]);
                float p1 = EXP2(st1[j]);
                unsigned u0, u1;
                __builtin_memcpy(&u0, &p0, 4); __builtin_memcpy(&u1, &p1, 4);
                pt0[j] = (short)((u0 + 0x8000u) >> 16);
                pt1[j] = (short)((u1 + 0x8000u) >> 16);
            }
#pragma unroll
            for (int nt = 0; nt < 4; ++nt) {   // O^T += V^T P^T
                s4v vf = *(const s4v*)(Vc + nt * 1024 + voff[t]);
                o[0][nt] = MFMA16(vf, pt0, o[0][nt]);
                o[1][nt] = MFMA16(vf, pt1, o[1][nt]);
            }
            ol[0] = MFMA16(ones, pt0, ol[0]);  // l += 1^T P^T
            ol[1] = MFMA16(ones, pt1, ol[1]);
        }
        __syncthreads();                       // drains prefetch vmcnt + barrier
        cur ^= 1;
    }
#undef STAGE
    // epilogue: store partial O (d = nt*16+quad*4+r, q = ln) + l
#pragma unroll
    for (int qs = 0; qs < 2; ++qs) {
        long qrow = (long)(sp * 16 + bh) * 2048 + q0 + qs * 16 + ln;
        if (quad == 0) Lp[qrow] = ol[qs][0];
#pragma unroll
        for (int nt = 0; nt < 4; ++nt)
            *(floatx4*)(Op + qrow * 64 + nt * 16 + quad * 4) = o[qs][nt];
    }
}

// ---------------------------------------------------------------------------
// Combine kv-split partials: O = sum_s Op / sum_s l -> Ob[b*s][256] bf16.
// Vectorized: 4 d-elems (float4) per thread, grid 2048 x 256.
__global__ __launch_bounds__(256) void combine_kernel(
    const float* __restrict__ Op, const float* __restrict__ Lp, short* __restrict__ Ob) {
    int idx = blockIdx.x * 256 + threadIdx.x;        // [0, 512K)
    int row = idx >> 4;                              // bh*2048 + q
    int d0 = (idx & 15) * 4;
    int bh = row >> 11, qq = row & 2047;
    int b = bh >> 2, h = bh & 3;
    float4 os = {0.f, 0.f, 0.f, 0.f};
    float ls = 0.f;
#pragma unroll
    for (int s = 0; s < 4; ++s) {
        long rr = (long)(s * 16 + bh) * 2048 + qq;
        float4 v = *(const float4*)(Op + rr * 64 + d0);
        os.x += v.x; os.y += v.y; os.z += v.z; os.w += v.w;
        ls += Lp[rr];
    }
    float li = 1.f / ls;
    s4v ov;
    ov[0] = f2b(os.x * li); ov[1] = f2b(os.y * li);
    ov[2] = f2b(os.z * li); ov[3] = f2b(os.w * li);
    *(s4v*)(Ob + ((long)(b * 2048 + qq)) * 256 + h * 64 + d0) = ov;
}

// ---------------------------------------------------------------------------
extern "C" void kernel_launch(void* const* d_in, const int* in_sizes, int n_in,
                              void* d_out, int out_size, void* d_ws, size_t ws_size,
                              hipStream_t stream) {
    const float* q   = (const float*)d_in[0];
    const int*   qc  = (const int*)d_in[1];
    const float* kv  = (const float*)d_in[2];
    const int*   kvc = (const int*)d_in[3];
    const float* Wq  = (const float*)d_in[4];
    const float* Wk  = (const float*)d_in[5];
    const float* Wv  = (const float*)d_in[6];
    const float* Wo  = (const float*)d_in[7];
    float* out = (float*)d_out;

    char* ws = (char*)d_ws;
    const size_t MB = 1024 * 1024;
    short* Wq_t  = (short*)(ws);                 // 0.5 MB  [256][1024]
    short* Wkv_t = (short*)(ws + MB / 2);        // 1.0 MB  [512][1024]
    short* Wo_t  = (short*)(ws + 3 * MB / 2);    // 0.5 MB  [1024][256]
    short* qb    = (short*)(ws + 2 * MB);        // 16 MB   [8192][1024] bf16
    short* kvb   = (short*)(ws + 18 * MB);       // 16 MB
    // rope outputs written directly by proj_gemm epilogue (no fp32 Qp/KVp):
    short* Qr    = (short*)(ws + 34 * MB);       // 4 MB  [16][2048][64]
    short* Kr    = (short*)(ws + 38 * MB);       // 4 MB
    short* Vt    = (short*)(ws + 42 * MB);       // 4 MB  [16][64][2048]
    short* Ob    = (short*)(ws + 46 * MB);       // 4 MB  [8192][256]
    float* Opart = (float*)(ws + 50 * MB);       // 32 MB [4 split][16 bh][2048 q][64 d]
    float* Lpart = (float*)(ws + 82 * MB);       // 0.5 MB [4][16][2048]

    hipLaunchKernelGGL(prep_all, dim3(4352), dim3(256), 0, stream,
                       Wq, Wk, Wv, Wo, q, kv, Wq_t, Wkv_t, Wo_t, qb, kvb);
    hipLaunchKernelGGL(proj_gemm, dim3(384), dim3(256), 0, stream,
                       qb, kvb, Wq_t, Wkv_t, qc, kvc, Qr, Kr, Vt);
    hipLaunchKernelGGL(attn_kernel, dim3(1024), dim3(256), 0, stream,
                       Qr, Kr, Vt, Opart, Lpart);
    hipLaunchKernelGGL(combine_kernel, dim3(2048), dim3(256), 0, stream,
                       Opart, Lpart, Ob);
    hipLaunchKernelGGL(final_gemm, dim3(64, 8), dim3(256), 0, stream, Ob, Wo_t, out);
}